// Round 10
// baseline (47.942 us; speedup 1.0000x reference)
//
#include <hip/hip_runtime.h>
#include <math.h>

#define D 256
#define COPY_FLOATS 1028   // 4 groups * 256 sums + 4 counts
#define NCOPIES_MAX 8      // R8-validated
#define GRID_BLOCKS 512    // x 512 thr = 4096 waves -> one 64-row chunk each
#define WAVES_PB 8

// R10: branch-free per-group 4-deep batches. Each group's mask is popped
// 4 rows at a time -> 4 independent loads -> pure adds into that group's
// accumulator (no per-row group tests). Leftovers (<4 per group) merge into
// a combined mask handled by the old wave-uniform-branch path.
__global__ __launch_bounds__(512) void group_partial(
    const float* __restrict__ F, const float* __restrict__ T,
    float* __restrict__ ws, int nRows, int ncopies)
{
    __shared__ float lsum[WAVES_PB][4][D];   // [wave][group][col] = 32 KB
    __shared__ float lcnt[WAVES_PB][4];      // [wave][group]

    const int tid  = threadIdx.x;
    const int lane = tid & 63;
    const int wav  = tid >> 6;               // 0..7
    const long long waveId = (long long)blockIdx.x * WAVES_PB + wav;
    const long long nWaves = (long long)gridDim.x * WAVES_PB;

    float4 a0 = {0.f,0.f,0.f,0.f}, a1 = a0, a2 = a0, a3 = a0;
    float c0 = 0.f, c1 = 0.f, c2 = 0.f, c3 = 0.f;

    for (long long base = waveId * 64; base < (long long)nRows;
         base += nWaves * 64) {
        const long long r = base + lane;
        const float t = (r < (long long)nRows) ? T[r] : 2.0f;  // sentinel

        // 64-bit ballots: bit i = membership of row base+i (wave-uniform)
        const unsigned long long m0 = __ballot(t <= 0.1f);
        const unsigned long long m1 = __ballot(t > 0.3f && t <= 0.4f);
        const unsigned long long m2 = __ballot(t > 0.6f && t <= 0.7f);
        const unsigned long long m3 = __ballot(t > 0.8f && t <= 1.1f);

        c0 += (float)__popcll(m0);
        c1 += (float)__popcll(m1);
        c2 += (float)__popcll(m2);
        c3 += (float)__popcll(m3);

        const float* Fb = F + (size_t)base * D + (size_t)lane * 4;

        // ---- branch-free phase: per-group 4-deep batches ----
        auto doGroup = [&](unsigned long long m, float4& acc) -> unsigned long long {
            while (__popcll(m) >= 4) {
                const int j0 = __ffsll(m) - 1; m &= m - 1;
                const int j1 = __ffsll(m) - 1; m &= m - 1;
                const int j2 = __ffsll(m) - 1; m &= m - 1;
                const int j3 = __ffsll(m) - 1; m &= m - 1;
                const float4 v0 = *reinterpret_cast<const float4*>(Fb + (size_t)j0 * D);
                const float4 v1 = *reinterpret_cast<const float4*>(Fb + (size_t)j1 * D);
                const float4 v2 = *reinterpret_cast<const float4*>(Fb + (size_t)j2 * D);
                const float4 v3 = *reinterpret_cast<const float4*>(Fb + (size_t)j3 * D);
                // tree-sum then one accumulate: 16 VALU adds, zero branches
                acc.x += (v0.x + v1.x) + (v2.x + v3.x);
                acc.y += (v0.y + v1.y) + (v2.y + v3.y);
                acc.z += (v0.z + v1.z) + (v2.z + v3.z);
                acc.w += (v0.w + v1.w) + (v2.w + v3.w);
            }
            return m;   // <4 leftover bits
        };

        unsigned long long rem = 0;
        rem |= doGroup(m0, a0);
        rem |= doGroup(m1, a1);
        rem |= doGroup(m2, a2);
        rem |= doGroup(m3, a3);

        // ---- leftover phase (<=12 rows): combined mask, branchy addRow ----
        auto addRow = [&](int jj, const float4& v) {
            if ((m0 >> jj) & 1ull) {
                a0.x += v.x; a0.y += v.y; a0.z += v.z; a0.w += v.w;
            } else if ((m1 >> jj) & 1ull) {
                a1.x += v.x; a1.y += v.y; a1.z += v.z; a1.w += v.w;
            } else if ((m2 >> jj) & 1ull) {
                a2.x += v.x; a2.y += v.y; a2.z += v.z; a2.w += v.w;
            } else {
                a3.x += v.x; a3.y += v.y; a3.z += v.z; a3.w += v.w;
            }
        };

        while (__popcll(rem) >= 4) {
            const int j0 = __ffsll(rem) - 1; rem &= rem - 1;
            const int j1 = __ffsll(rem) - 1; rem &= rem - 1;
            const int j2 = __ffsll(rem) - 1; rem &= rem - 1;
            const int j3 = __ffsll(rem) - 1; rem &= rem - 1;
            const float4 v0 = *reinterpret_cast<const float4*>(Fb + (size_t)j0 * D);
            const float4 v1 = *reinterpret_cast<const float4*>(Fb + (size_t)j1 * D);
            const float4 v2 = *reinterpret_cast<const float4*>(Fb + (size_t)j2 * D);
            const float4 v3 = *reinterpret_cast<const float4*>(Fb + (size_t)j3 * D);
            addRow(j0, v0); addRow(j1, v1); addRow(j2, v2); addRow(j3, v3);
        }
        while (rem) {
            const int j0 = __ffsll(rem) - 1; rem &= rem - 1;
            const float4 v0 = *reinterpret_cast<const float4*>(Fb + (size_t)j0 * D);
            addRow(j0, v0);
        }
    }

    // per-wave partials -> LDS
    *reinterpret_cast<float4*>(&lsum[wav][0][lane * 4]) = a0;
    *reinterpret_cast<float4*>(&lsum[wav][1][lane * 4]) = a1;
    *reinterpret_cast<float4*>(&lsum[wav][2][lane * 4]) = a2;
    *reinterpret_cast<float4*>(&lsum[wav][3][lane * 4]) = a3;
    if (lane == 0) {
        lcnt[wav][0] = c0; lcnt[wav][1] = c1; lcnt[wav][2] = c2; lcnt[wav][3] = c3;
    }
    __syncthreads();

    // block reduce across 8 waves: threads 0-255 handle groups 0,1;
    // threads 256-511 handle groups 2,3 -> 2 atomics per thread
    float* dst = ws + (size_t)(blockIdx.x % ncopies) * COPY_FLOATS;
    const int col  = tid & 255;
    const int gsel = (tid >> 8) * 2;   // 0 or 2
#pragma unroll
    for (int gg = 0; gg < 2; ++gg) {
        const int g = gsel + gg;
        float s = 0.f;
#pragma unroll
        for (int w = 0; w < WAVES_PB; ++w) s += lsum[w][g][col];
        atomicAdd(dst + g * D + col, s);
    }
    if (tid < 4) {
        float c = 0.f;
#pragma unroll
        for (int w = 0; w < WAVES_PB; ++w) c += lcnt[w][tid];
        atomicAdd(dst + 4 * D + tid, c);
    }
}

__global__ __launch_bounds__(256) void finalize(
    const float* __restrict__ ws, int ncopies, float* __restrict__ out)
{
    const int tid  = threadIdx.x;
    const int lane = tid & 63;
    const int wav  = tid >> 6;

    float s[4] = {0.f,0.f,0.f,0.f};
    float c[4] = {0.f,0.f,0.f,0.f};
#pragma unroll 8
    for (int cp = 0; cp < ncopies; ++cp) {
        const float* w = ws + (size_t)cp * COPY_FLOATS;
#pragma unroll
        for (int g = 0; g < 4; ++g) {
            s[g] += w[g * D + tid];
            c[g] += w[4 * D + g];
        }
    }

    float m[4];
#pragma unroll
    for (int g = 0; g < 4; ++g)
        m[g] = (c[g] > 0.f) ? s[g] / fmaxf(c[g], 1.f) : 0.f;

    float p[6];
    p[0] = (m[0]-m[1]) * (m[0]-m[1]);   // d12
    p[1] = (m[0]-m[2]) * (m[0]-m[2]);   // d13
    p[2] = (m[0]-m[3]) * (m[0]-m[3]);   // d14
    p[3] = (m[1]-m[2]) * (m[1]-m[2]);   // d23
    p[4] = (m[1]-m[3]) * (m[1]-m[3]);   // d24
    p[5] = (m[2]-m[3]) * (m[2]-m[3]);   // d34

    __shared__ float red[6][4];
#pragma unroll
    for (int k = 0; k < 6; ++k) {
        float v = p[k];
#pragma unroll
        for (int off = 32; off >= 1; off >>= 1)
            v += __shfl_down(v, off, 64);
        if (lane == 0) red[k][wav] = v;
    }
    __syncthreads();

    if (tid == 0) {
        float d[6];
#pragma unroll
        for (int k = 0; k < 6; ++k)
            d[k] = sqrtf(red[k][0] + red[k][1] + red[k][2] + red[k][3]);
        const float d12 = d[0], d13 = d[1], d14 = d[2];
        const float d23 = d[3], d24 = d[4], d34 = d[5];
        const float M = 0.75f;
        const float loss =
              fmaxf(d12 - d13 + M, 0.f)       + fmaxf(d12 - d14 + 2.f * M, 0.f)
            + fmaxf(d23 - d24 + M, 0.f)       + fmaxf(d23 - d14 + 2.f * M, 0.f)
            + fmaxf(d34 - d24 + M, 0.f)       + fmaxf(d34 - d14 + 2.f * M, 0.f);
        out[0] = loss;
    }
}

extern "C" void kernel_launch(void* const* d_in, const int* in_sizes, int n_in,
                              void* d_out, int out_size, void* d_ws, size_t ws_size,
                              hipStream_t stream) {
    const float* F = (const float*)d_in[0];   // feature_results [N, 256] fp32
    const float* T = (const float*)d_in[1];   // target_var [N] fp32
    float* out = (float*)d_out;
    const int nRows = in_sizes[1];

    int ncopies = (int)(ws_size / (COPY_FLOATS * sizeof(float)));
    if (ncopies > NCOPIES_MAX) ncopies = NCOPIES_MAX;
    if (ncopies < 1) ncopies = 1;

    // atomics accumulate into ws -> must re-zero every launch (capture-safe)
    hipMemsetAsync(d_ws, 0, (size_t)ncopies * COPY_FLOATS * sizeof(float), stream);

    group_partial<<<GRID_BLOCKS, 512, 0, stream>>>(F, T, (float*)d_ws, nRows, ncopies);
    finalize<<<1, 256, 0, stream>>>((const float*)d_ws, ncopies, out);
}

// Round 11
// 46.541 us; speedup vs baseline: 1.0301x; 1.0301x over previous
//
#include <hip/hip_runtime.h>
#include <math.h>

#define D 256
#define COPY_FLOATS 1028   // 4 groups * 256 sums + 4 counts
#define NCOPIES_MAX 8      // R8-validated; slot=b%8 keeps each copy XCD-local
#define GRID_BLOCKS 256    // R11: x 512 thr = 2048 waves, 2 chunks each
#define WAVES_PB 8

// Main kernel (R3/R8/R9-validated pattern): each wave owns contiguous 64-row
// chunks. Coalesced 64-lane T load -> 64-bit ballots -> member mask in SGPRs
// (wave-uniform). Member rows popped 4 at a time from the COMBINED mask
// (single loop -- R10's per-group split regressed): 4 independent
// global_load_dwordx4 in flight before any consume.
// R11 change: 256 blocks (1/CU, 2048 wave-streams, 2 chunks per wave) --
// probing the DRAM-stream-locality curve: 8192str=49.4, 4096str=42.5.
__global__ __launch_bounds__(512) void group_partial(
    const float* __restrict__ F, const float* __restrict__ T,
    float* __restrict__ ws, int nRows, int ncopies)
{
    __shared__ float lsum[WAVES_PB][4][D];   // [wave][group][col] = 32 KB
    __shared__ float lcnt[WAVES_PB][4];      // [wave][group]

    const int tid  = threadIdx.x;
    const int lane = tid & 63;
    const int wav  = tid >> 6;               // 0..7
    const long long waveId = (long long)blockIdx.x * WAVES_PB + wav;
    const long long nWaves = (long long)gridDim.x * WAVES_PB;

    float4 a0 = {0.f,0.f,0.f,0.f}, a1 = a0, a2 = a0, a3 = a0;
    float c0 = 0.f, c1 = 0.f, c2 = 0.f, c3 = 0.f;

    for (long long base = waveId * 64; base < (long long)nRows;
         base += nWaves * 64) {
        const long long r = base + lane;
        const float t = (r < (long long)nRows) ? T[r] : 2.0f;  // sentinel

        // 64-bit ballots: bit i = membership of row base+i (wave-uniform)
        const unsigned long long m0 = __ballot(t <= 0.1f);
        const unsigned long long m1 = __ballot(t > 0.3f && t <= 0.4f);
        const unsigned long long m2 = __ballot(t > 0.6f && t <= 0.7f);
        const unsigned long long m3 = __ballot(t > 0.8f && t <= 1.1f);

        c0 += (float)__popcll(m0);
        c1 += (float)__popcll(m1);
        c2 += (float)__popcll(m2);
        c3 += (float)__popcll(m3);

        const float* Fb = F + (size_t)base * D + (size_t)lane * 4;
        unsigned long long mAll = m0 | m1 | m2 | m3;

        auto addRow = [&](int jj, const float4& v) {
            // jj and mask bits are wave-uniform -> scalar branch, no divergence
            if ((m0 >> jj) & 1ull) {
                a0.x += v.x; a0.y += v.y; a0.z += v.z; a0.w += v.w;
            } else if ((m1 >> jj) & 1ull) {
                a1.x += v.x; a1.y += v.y; a1.z += v.z; a1.w += v.w;
            } else if ((m2 >> jj) & 1ull) {
                a2.x += v.x; a2.y += v.y; a2.z += v.z; a2.w += v.w;
            } else {
                a3.x += v.x; a3.y += v.y; a3.z += v.z; a3.w += v.w;
            }
        };

        // 4-wide body: 4 independent 1KB row loads in flight per wave
        while (__popcll(mAll) >= 4) {
            const int j0 = __ffsll(mAll) - 1; mAll &= mAll - 1;
            const int j1 = __ffsll(mAll) - 1; mAll &= mAll - 1;
            const int j2 = __ffsll(mAll) - 1; mAll &= mAll - 1;
            const int j3 = __ffsll(mAll) - 1; mAll &= mAll - 1;
            const float4 v0 = *reinterpret_cast<const float4*>(Fb + (size_t)j0 * D);
            const float4 v1 = *reinterpret_cast<const float4*>(Fb + (size_t)j1 * D);
            const float4 v2 = *reinterpret_cast<const float4*>(Fb + (size_t)j2 * D);
            const float4 v3 = *reinterpret_cast<const float4*>(Fb + (size_t)j3 * D);
            addRow(j0, v0); addRow(j1, v1); addRow(j2, v2); addRow(j3, v3);
        }
        while (mAll) {
            const int j0 = __ffsll(mAll) - 1; mAll &= mAll - 1;
            const float4 v0 = *reinterpret_cast<const float4*>(Fb + (size_t)j0 * D);
            addRow(j0, v0);
        }
    }

    // per-wave partials -> LDS
    *reinterpret_cast<float4*>(&lsum[wav][0][lane * 4]) = a0;
    *reinterpret_cast<float4*>(&lsum[wav][1][lane * 4]) = a1;
    *reinterpret_cast<float4*>(&lsum[wav][2][lane * 4]) = a2;
    *reinterpret_cast<float4*>(&lsum[wav][3][lane * 4]) = a3;
    if (lane == 0) {
        lcnt[wav][0] = c0; lcnt[wav][1] = c1; lcnt[wav][2] = c2; lcnt[wav][3] = c3;
    }
    __syncthreads();

    // block reduce across 8 waves: threads 0-255 handle groups 0,1;
    // threads 256-511 handle groups 2,3 -> 2 atomics per thread
    float* dst = ws + (size_t)(blockIdx.x % ncopies) * COPY_FLOATS;
    const int col  = tid & 255;
    const int gsel = (tid >> 8) * 2;   // 0 or 2
#pragma unroll
    for (int gg = 0; gg < 2; ++gg) {
        const int g = gsel + gg;
        float s = 0.f;
#pragma unroll
        for (int w = 0; w < WAVES_PB; ++w) s += lsum[w][g][col];
        atomicAdd(dst + g * D + col, s);
    }
    if (tid < 4) {
        float c = 0.f;
#pragma unroll
        for (int w = 0; w < WAVES_PB; ++w) c += lcnt[w][tid];
        atomicAdd(dst + 4 * D + tid, c);
    }
}

__global__ __launch_bounds__(256) void finalize(
    const float* __restrict__ ws, int ncopies, float* __restrict__ out)
{
    const int tid  = threadIdx.x;
    const int lane = tid & 63;
    const int wav  = tid >> 6;

    float s[4] = {0.f,0.f,0.f,0.f};
    float c[4] = {0.f,0.f,0.f,0.f};
#pragma unroll 8
    for (int cp = 0; cp < ncopies; ++cp) {
        const float* w = ws + (size_t)cp * COPY_FLOATS;
#pragma unroll
        for (int g = 0; g < 4; ++g) {
            s[g] += w[g * D + tid];
            c[g] += w[4 * D + g];
        }
    }

    float m[4];
#pragma unroll
    for (int g = 0; g < 4; ++g)
        m[g] = (c[g] > 0.f) ? s[g] / fmaxf(c[g], 1.f) : 0.f;

    float p[6];
    p[0] = (m[0]-m[1]) * (m[0]-m[1]);   // d12
    p[1] = (m[0]-m[2]) * (m[0]-m[2]);   // d13
    p[2] = (m[0]-m[3]) * (m[0]-m[3]);   // d14
    p[3] = (m[1]-m[2]) * (m[1]-m[2]);   // d23
    p[4] = (m[1]-m[3]) * (m[1]-m[3]);   // d24
    p[5] = (m[2]-m[3]) * (m[2]-m[3]);   // d34

    __shared__ float red[6][4];
#pragma unroll
    for (int k = 0; k < 6; ++k) {
        float v = p[k];
#pragma unroll
        for (int off = 32; off >= 1; off >>= 1)
            v += __shfl_down(v, off, 64);
        if (lane == 0) red[k][wav] = v;
    }
    __syncthreads();

    if (tid == 0) {
        float d[6];
#pragma unroll
        for (int k = 0; k < 6; ++k)
            d[k] = sqrtf(red[k][0] + red[k][1] + red[k][2] + red[k][3]);
        const float d12 = d[0], d13 = d[1], d14 = d[2];
        const float d23 = d[3], d24 = d[4], d34 = d[5];
        const float M = 0.75f;
        const float loss =
              fmaxf(d12 - d13 + M, 0.f)       + fmaxf(d12 - d14 + 2.f * M, 0.f)
            + fmaxf(d23 - d24 + M, 0.f)       + fmaxf(d23 - d14 + 2.f * M, 0.f)
            + fmaxf(d34 - d24 + M, 0.f)       + fmaxf(d34 - d14 + 2.f * M, 0.f);
        out[0] = loss;
    }
}

extern "C" void kernel_launch(void* const* d_in, const int* in_sizes, int n_in,
                              void* d_out, int out_size, void* d_ws, size_t ws_size,
                              hipStream_t stream) {
    const float* F = (const float*)d_in[0];   // feature_results [N, 256] fp32
    const float* T = (const float*)d_in[1];   // target_var [N] fp32
    float* out = (float*)d_out;
    const int nRows = in_sizes[1];

    int ncopies = (int)(ws_size / (COPY_FLOATS * sizeof(float)));
    if (ncopies > NCOPIES_MAX) ncopies = NCOPIES_MAX;
    if (ncopies < 1) ncopies = 1;

    // atomics accumulate into ws -> must re-zero every launch (capture-safe)
    hipMemsetAsync(d_ws, 0, (size_t)ncopies * COPY_FLOATS * sizeof(float), stream);

    group_partial<<<GRID_BLOCKS, 512, 0, stream>>>(F, T, (float*)d_ws, nRows, ncopies);
    finalize<<<1, 256, 0, stream>>>((const float*)d_ws, ncopies, out);
}

// Round 12
// 41.407 us; speedup vs baseline: 1.1578x; 1.1240x over previous
//
#include <hip/hip_runtime.h>
#include <math.h>

#define D 256
#define COPY_FLOATS 1028   // 4 groups * 256 sums + 4 counts
#define NCOPIES_MAX 8      // R8-validated; slot=b%8 keeps each copy XCD-local
#define GRID_BLOCKS 512    // R9-validated optimum: 4096 wave-streams
#define WAVES_PB 8

// FINAL (R9 config, validated best = 42.5 us):
// - each wave owns one contiguous 64-row chunk (4096 waves, 1 chunk each)
//   [stream-count curve bracketed: 8192=49.4, 4096=42.5, 2048=46.5]
// - coalesced 64-lane T load -> 64-bit ballots -> member masks in SGPRs
//   (wave-uniform row skip: only ~50% of F is ever fetched)
// - combined mask popped 4 rows/batch -> 4 independent global_load_dwordx4
//   in flight before any consume [1-deep=51.8, 4-deep=45.3, 8-deep=74 spill]
// - per-row accumulator select via wave-uniform scalar branch
//   [per-group branch-free split regressed: R10]
// - 8-wave LDS reduce -> spread atomics into 8 ws copies [ncopies 32->8: -2.7us]
// - separate tiny finalize dispatch [fusion regressed 3x: R2/R4/R7]
__global__ __launch_bounds__(512) void group_partial(
    const float* __restrict__ F, const float* __restrict__ T,
    float* __restrict__ ws, int nRows, int ncopies)
{
    __shared__ float lsum[WAVES_PB][4][D];   // [wave][group][col] = 32 KB
    __shared__ float lcnt[WAVES_PB][4];      // [wave][group]

    const int tid  = threadIdx.x;
    const int lane = tid & 63;
    const int wav  = tid >> 6;               // 0..7
    const long long waveId = (long long)blockIdx.x * WAVES_PB + wav;
    const long long nWaves = (long long)gridDim.x * WAVES_PB;

    float4 a0 = {0.f,0.f,0.f,0.f}, a1 = a0, a2 = a0, a3 = a0;
    float c0 = 0.f, c1 = 0.f, c2 = 0.f, c3 = 0.f;

    for (long long base = waveId * 64; base < (long long)nRows;
         base += nWaves * 64) {
        const long long r = base + lane;
        const float t = (r < (long long)nRows) ? T[r] : 2.0f;  // sentinel

        // 64-bit ballots: bit i = membership of row base+i (wave-uniform)
        const unsigned long long m0 = __ballot(t <= 0.1f);
        const unsigned long long m1 = __ballot(t > 0.3f && t <= 0.4f);
        const unsigned long long m2 = __ballot(t > 0.6f && t <= 0.7f);
        const unsigned long long m3 = __ballot(t > 0.8f && t <= 1.1f);

        c0 += (float)__popcll(m0);
        c1 += (float)__popcll(m1);
        c2 += (float)__popcll(m2);
        c3 += (float)__popcll(m3);

        const float* Fb = F + (size_t)base * D + (size_t)lane * 4;
        unsigned long long mAll = m0 | m1 | m2 | m3;

        auto addRow = [&](int jj, const float4& v) {
            // jj and mask bits are wave-uniform -> scalar branch, no divergence
            if ((m0 >> jj) & 1ull) {
                a0.x += v.x; a0.y += v.y; a0.z += v.z; a0.w += v.w;
            } else if ((m1 >> jj) & 1ull) {
                a1.x += v.x; a1.y += v.y; a1.z += v.z; a1.w += v.w;
            } else if ((m2 >> jj) & 1ull) {
                a2.x += v.x; a2.y += v.y; a2.z += v.z; a2.w += v.w;
            } else {
                a3.x += v.x; a3.y += v.y; a3.z += v.z; a3.w += v.w;
            }
        };

        // 4-wide body: 4 independent 1KB row loads in flight per wave
        while (__popcll(mAll) >= 4) {
            const int j0 = __ffsll(mAll) - 1; mAll &= mAll - 1;
            const int j1 = __ffsll(mAll) - 1; mAll &= mAll - 1;
            const int j2 = __ffsll(mAll) - 1; mAll &= mAll - 1;
            const int j3 = __ffsll(mAll) - 1; mAll &= mAll - 1;
            const float4 v0 = *reinterpret_cast<const float4*>(Fb + (size_t)j0 * D);
            const float4 v1 = *reinterpret_cast<const float4*>(Fb + (size_t)j1 * D);
            const float4 v2 = *reinterpret_cast<const float4*>(Fb + (size_t)j2 * D);
            const float4 v3 = *reinterpret_cast<const float4*>(Fb + (size_t)j3 * D);
            addRow(j0, v0); addRow(j1, v1); addRow(j2, v2); addRow(j3, v3);
        }
        while (mAll) {
            const int j0 = __ffsll(mAll) - 1; mAll &= mAll - 1;
            const float4 v0 = *reinterpret_cast<const float4*>(Fb + (size_t)j0 * D);
            addRow(j0, v0);
        }
    }

    // per-wave partials -> LDS
    *reinterpret_cast<float4*>(&lsum[wav][0][lane * 4]) = a0;
    *reinterpret_cast<float4*>(&lsum[wav][1][lane * 4]) = a1;
    *reinterpret_cast<float4*>(&lsum[wav][2][lane * 4]) = a2;
    *reinterpret_cast<float4*>(&lsum[wav][3][lane * 4]) = a3;
    if (lane == 0) {
        lcnt[wav][0] = c0; lcnt[wav][1] = c1; lcnt[wav][2] = c2; lcnt[wav][3] = c3;
    }
    __syncthreads();

    // block reduce across 8 waves: threads 0-255 handle groups 0,1;
    // threads 256-511 handle groups 2,3 -> 2 atomics per thread
    float* dst = ws + (size_t)(blockIdx.x % ncopies) * COPY_FLOATS;
    const int col  = tid & 255;
    const int gsel = (tid >> 8) * 2;   // 0 or 2
#pragma unroll
    for (int gg = 0; gg < 2; ++gg) {
        const int g = gsel + gg;
        float s = 0.f;
#pragma unroll
        for (int w = 0; w < WAVES_PB; ++w) s += lsum[w][g][col];
        atomicAdd(dst + g * D + col, s);
    }
    if (tid < 4) {
        float c = 0.f;
#pragma unroll
        for (int w = 0; w < WAVES_PB; ++w) c += lcnt[w][tid];
        atomicAdd(dst + 4 * D + tid, c);
    }
}

__global__ __launch_bounds__(256) void finalize(
    const float* __restrict__ ws, int ncopies, float* __restrict__ out)
{
    const int tid  = threadIdx.x;
    const int lane = tid & 63;
    const int wav  = tid >> 6;

    float s[4] = {0.f,0.f,0.f,0.f};
    float c[4] = {0.f,0.f,0.f,0.f};
#pragma unroll 8
    for (int cp = 0; cp < ncopies; ++cp) {
        const float* w = ws + (size_t)cp * COPY_FLOATS;
#pragma unroll
        for (int g = 0; g < 4; ++g) {
            s[g] += w[g * D + tid];
            c[g] += w[4 * D + g];
        }
    }

    float m[4];
#pragma unroll
    for (int g = 0; g < 4; ++g)
        m[g] = (c[g] > 0.f) ? s[g] / fmaxf(c[g], 1.f) : 0.f;

    float p[6];
    p[0] = (m[0]-m[1]) * (m[0]-m[1]);   // d12
    p[1] = (m[0]-m[2]) * (m[0]-m[2]);   // d13
    p[2] = (m[0]-m[3]) * (m[0]-m[3]);   // d14
    p[3] = (m[1]-m[2]) * (m[1]-m[2]);   // d23
    p[4] = (m[1]-m[3]) * (m[1]-m[3]);   // d24
    p[5] = (m[2]-m[3]) * (m[2]-m[3]);   // d34

    __shared__ float red[6][4];
#pragma unroll
    for (int k = 0; k < 6; ++k) {
        float v = p[k];
#pragma unroll
        for (int off = 32; off >= 1; off >>= 1)
            v += __shfl_down(v, off, 64);
        if (lane == 0) red[k][wav] = v;
    }
    __syncthreads();

    if (tid == 0) {
        float d[6];
#pragma unroll
        for (int k = 0; k < 6; ++k)
            d[k] = sqrtf(red[k][0] + red[k][1] + red[k][2] + red[k][3]);
        const float d12 = d[0], d13 = d[1], d14 = d[2];
        const float d23 = d[3], d24 = d[4], d34 = d[5];
        const float M = 0.75f;
        const float loss =
              fmaxf(d12 - d13 + M, 0.f)       + fmaxf(d12 - d14 + 2.f * M, 0.f)
            + fmaxf(d23 - d24 + M, 0.f)       + fmaxf(d23 - d14 + 2.f * M, 0.f)
            + fmaxf(d34 - d24 + M, 0.f)       + fmaxf(d34 - d14 + 2.f * M, 0.f);
        out[0] = loss;
    }
}

extern "C" void kernel_launch(void* const* d_in, const int* in_sizes, int n_in,
                              void* d_out, int out_size, void* d_ws, size_t ws_size,
                              hipStream_t stream) {
    const float* F = (const float*)d_in[0];   // feature_results [N, 256] fp32
    const float* T = (const float*)d_in[1];   // target_var [N] fp32
    float* out = (float*)d_out;
    const int nRows = in_sizes[1];

    int ncopies = (int)(ws_size / (COPY_FLOATS * sizeof(float)));
    if (ncopies > NCOPIES_MAX) ncopies = NCOPIES_MAX;
    if (ncopies < 1) ncopies = 1;

    // atomics accumulate into ws -> must re-zero every launch (capture-safe)
    hipMemsetAsync(d_ws, 0, (size_t)ncopies * COPY_FLOATS * sizeof(float), stream);

    group_partial<<<GRID_BLOCKS, 512, 0, stream>>>(F, T, (float*)d_ws, nRows, ncopies);
    finalize<<<1, 256, 0, stream>>>((const float*)d_ws, ncopies, out);
}